// Round 4
// baseline (499.363 us; speedup 1.0000x reference)
//
#include <hip/hip_runtime.h>
#include <hip/hip_bf16.h>

#define B_ 4096
#define I_ 1024
#define H_ 2048
#define O_ 1024
#define K1 (I_ + H_)   // 3072
#define N1 (4 * H_)    // 8192
#define KT (K1 / 32)   // 96 K-tiles

typedef short v8s __attribute__((ext_vector_type(8)));
typedef float v4f __attribute__((ext_vector_type(4)));

__device__ __forceinline__ ushort f2bf(float f) {
    unsigned u = __float_as_uint(f);
    u += 0x7fffu + ((u >> 16) & 1u);   // RNE
    return (ushort)(u >> 16);
}
__device__ __forceinline__ float sigm(float x) { return 1.f / (1.f + __expf(-x)); }
__device__ __forceinline__ float tanh_f(float x) {
    x = fminf(15.f, fmaxf(-15.f, x));
    float e = __expf(2.f * x);
    return (e - 1.f) / (e + 1.f);
}
__device__ __forceinline__ void gload16(const void* g, void* l) {
    __builtin_amdgcn_global_load_lds(
        (const __attribute__((address_space(1))) void*)g,
        (__attribute__((address_space(3))) void*)l, 16, 0, 0);
}

// ---------------------------------------------------------------- conversion
__global__ __launch_bounds__(384) void convert_w(
    const float* __restrict__ Wxi, const float* __restrict__ Whi,
    const float* __restrict__ Wxf, const float* __restrict__ Whf,
    const float* __restrict__ Wxc, const float* __restrict__ Whc,
    const float* __restrict__ Wxo, const float* __restrict__ Who,
    ushort* __restrict__ Wcat)
{
    const int n = blockIdx.x;          // 0..8191
    const int k = threadIdx.x * 8;     // 0..3064
    const int h = n >> 2, g = n & 3;
    const float* src;
    if (k < I_) {
        const float* W = (g == 0) ? Wxi : (g == 1) ? Wxf : (g == 2) ? Wxc : Wxo;
        src = W + (size_t)h * I_ + k;
    } else {
        const float* W = (g == 0) ? Whi : (g == 1) ? Whf : (g == 2) ? Whc : Who;
        src = W + (size_t)h * H_ + (k - I_);
    }
    float4 a = *(const float4*)src;
    float4 b = *(const float4*)(src + 4);
    *(ushort4*)&Wcat[(size_t)n * K1 + k] =
        make_ushort4(f2bf(a.x), f2bf(a.y), f2bf(a.z), f2bf(a.w));
    *(ushort4*)&Wcat[(size_t)n * K1 + k + 4] =
        make_ushort4(f2bf(b.x), f2bf(b.y), f2bf(b.z), f2bf(b.w));
}

__global__ __launch_bounds__(384) void convert_x(
    const float* __restrict__ x, const float* __restrict__ hs, ushort* __restrict__ Xcat)
{
    const int m = blockIdx.x;
    const int k = threadIdx.x * 8;
    const float* src = (k < I_) ? (x + (size_t)m * I_ + k)
                                : (hs + (size_t)m * H_ + (k - I_));
    float4 a = *(const float4*)src;
    float4 b = *(const float4*)(src + 4);
    *(ushort4*)&Xcat[(size_t)m * K1 + k] =
        make_ushort4(f2bf(a.x), f2bf(a.y), f2bf(a.z), f2bf(a.w));
    *(ushort4*)&Xcat[(size_t)m * K1 + k + 4] =
        make_ushort4(f2bf(b.x), f2bf(b.y), f2bf(b.z), f2bf(b.w));
}

__global__ __launch_bounds__(256) void convert_y(
    const float* __restrict__ Why, ushort* __restrict__ WhyB)
{
    const int n = blockIdx.x;
    const int k = threadIdx.x * 8;
    const float* src = Why + (size_t)n * H_ + k;
    float4 a = *(const float4*)src;
    float4 b = *(const float4*)(src + 4);
    *(ushort4*)&WhyB[(size_t)n * H_ + k] =
        make_ushort4(f2bf(a.x), f2bf(a.y), f2bf(a.z), f2bf(a.w));
    *(ushort4*)&WhyB[(size_t)n * H_ + k + 4] =
        make_ushort4(f2bf(b.x), f2bf(b.y), f2bf(b.z), f2bf(b.w));
}

// ---------------------------------------------------------------------------
// GEMM1: 256x256 tile, BK=32, 8 waves, 4-deep LDS ring, counted vmcnt,
// XOR-swizzled LDS: linear L holds logical u = L ^ (((L>>7)&7)<<4).
// Read side MUST apply the same XOR to the FULL byte address (bit 6 is the
// row-parity bit — adding instead of XOR-ing was the round-3 bug).
// ---------------------------------------------------------------------------

#define STAGE(BUF, TT) {                                              \
    const size_t ko = (size_t)(TT) * 32;                              \
    ushort* a2 = (ushort*)lds + (BUF) * 8192;                         \
    ushort* b2 = (ushort*)lds + 32768 + (BUF) * 8192;                 \
    gload16(aSrc0 + ko, a2 + w * 512);                                \
    gload16(aSrc1 + ko, a2 + 4096 + w * 512);                         \
    gload16(bSrc0 + ko, b2 + w * 512);                                \
    gload16(bSrc1 + ko, b2 + 4096 + w * 512);                         \
}

#define STEP(BUF, TT, VMSTR, DOSTAGE) {                               \
    asm volatile("s_waitcnt vmcnt(" VMSTR ")" ::: "memory");          \
    __builtin_amdgcn_s_barrier();                                     \
    __builtin_amdgcn_sched_barrier(0);                                \
    const ushort* ab = (const ushort*)lds + (BUF) * 8192;             \
    const ushort* bb = (const ushort*)lds + 32768 + (BUF) * 8192;     \
    v8s afr[8], bfr[4];                                               \
    _Pragma("unroll")                                                 \
    for (int mi = 0; mi < 8; ++mi)                                    \
        afr[mi] = *(const v8s*)&ab[aoffU + mi * 512];                 \
    _Pragma("unroll")                                                 \
    for (int ni = 0; ni < 4; ++ni)                                    \
        bfr[ni] = *(const v8s*)&bb[boffU + ni * 512];                 \
    if (DOSTAGE) { STAGE(((BUF) + 3) & 3, (TT) + 3) }                 \
    __builtin_amdgcn_s_setprio(1);                                    \
    _Pragma("unroll")                                                 \
    for (int mi = 0; mi < 8; ++mi)                                    \
      _Pragma("unroll")                                               \
      for (int ni = 0; ni < 4; ++ni)                                  \
        acc[mi][ni] = __builtin_amdgcn_mfma_f32_16x16x32_bf16(        \
            afr[mi], bfr[ni], acc[mi][ni], 0, 0, 0);                  \
    __builtin_amdgcn_s_setprio(0);                                    \
}

__global__ __launch_bounds__(512, 2) void gates_mm_256(
    const ushort* __restrict__ A, const ushort* __restrict__ Bm,
    const float* __restrict__ cs,
    const float* __restrict__ bxi, const float* __restrict__ bxf,
    const float* __restrict__ bxc, const float* __restrict__ bxo,
    float* __restrict__ hid_out, float* __restrict__ cell_out,
    ushort* __restrict__ hidB)
{
    __shared__ ushort lds[65536];   // 128 KB: A ring 4x16KB | B ring 4x16KB

    const int tid  = threadIdx.x;
    const int lane = tid & 63;
    const int w    = tid >> 6;          // wave 0..7
    const int wm   = w >> 2;            // 0..1  (M half)
    const int wn   = w & 3;             // 0..3  (N quarter)

    // XCD-aware block swizzle (512 blocks, 512%8==0)
    const int nwg = gridDim.x;
    const int xid = (blockIdx.x & 7) * (nwg >> 3) + (blockIdx.x >> 3);
    const int blkM = xid & 15;          // 16 M-blocks
    const int blkN = xid >> 4;          // 32 N-blocks (consecutive ids share blkN)

    // ---- staging addresses (source pre-swizzle; LDS dest is linear)
    const int u    = (tid * 16) ^ (((tid >> 3) & 7) << 4);  // logical byte in 8KB half
    const int srow = u >> 6;            // 0..127
    const int scolE = (u & 63) >> 1;    // elem 0..31 (multiple of 8 -> 16B aligned)
    const ushort* aSrc0 = A  + (size_t)(blkM * 256 +       srow) * K1 + scolE;
    const ushort* aSrc1 = A  + (size_t)(blkM * 256 + 128 + srow) * K1 + scolE;
    const ushort* bSrc0 = Bm + (size_t)(blkN * 256 +       srow) * K1 + scolE;
    const ushort* bSrc1 = Bm + (size_t)(blkN * 256 + 128 + srow) * K1 + scolE;

    // ---- fragment read offsets: XOR the FULL byte address (bug fix)
    const int l15 = lane & 15, l4 = lane >> 4;
    const int flip = ((l15 >> 1) & 7) << 4;   // = ((u>>7)&7)<<4 for our rows
    const int aoffU = (((wm * 128 + l15) * 64 + l4 * 16) ^ flip) >> 1;
    const int boffU = (((wn * 64  + l15) * 64 + l4 * 16) ^ flip) >> 1;

    v4f acc[8][4];
    #pragma unroll
    for (int mi = 0; mi < 8; ++mi)
      #pragma unroll
      for (int ni = 0; ni < 4; ++ni) acc[mi][ni] = (v4f)0.f;

    // ---- prologue: prefetch tiles 0,1,2
    STAGE(0, 0) STAGE(1, 1) STAGE(2, 2)

    // ---- main loop: 96 K-tiles, counted vmcnt (never 0 until tail)
    #pragma unroll 1
    for (int T = 0; T < 92; T += 4) {
        STEP(0, T + 0, "8", true)
        STEP(1, T + 1, "8", true)
        STEP(2, T + 2, "8", true)
        STEP(3, T + 3, "8", true)
    }
    STEP(0, 92, "8", true)
    STEP(1, 93, "8", false)
    STEP(2, 94, "4", false)
    STEP(3, 95, "0", false)

    // ---- fused LSTM epilogue (quad lanes = gates i,f,c,o of one hidden unit)
    const int g = lane & 3;
    const int q = lane & 60;
    int hj[4]; float biasj[4];
    #pragma unroll
    for (int ni = 0; ni < 4; ++ni) {
        const int n = blkN * 256 + wn * 64 + ni * 16 + l15;
        hj[ni] = n >> 2;
        const float* bp = (g == 0) ? bxi : (g == 1) ? bxf : (g == 2) ? bxc : bxo;
        biasj[ni] = bp[hj[ni]];
    }
    #pragma unroll
    for (int mi = 0; mi < 8; ++mi) {
      #pragma unroll
      for (int r = 0; r < 4; ++r) {
        const int m = blkM * 256 + wm * 128 + mi * 16 + l4 * 4 + r;
        #pragma unroll
        for (int ni = 0; ni < 4; ++ni) {
            const float v = acc[mi][ni][r] + biasj[ni];
            const float gi = __shfl(v, q + 0, 64);
            const float gf = __shfl(v, q + 1, 64);
            const float gc = __shfl(v, q + 2, 64);
            const float go = __shfl(v, q + 3, 64);
            const float Ig = sigm(gi), Fg = sigm(gf);
            const float Cg = tanh_f(gc), Og = sigm(go);
            const int h = hj[ni];
            const float c_old = cs[(size_t)m * H_ + h];
            const float c_new = Fg * c_old + Ig * Cg;
            const float h_new = Og * tanh_f(c_new);
            if (g == 0)      cell_out[(size_t)m * H_ + h] = c_new;
            else if (g == 1) hid_out [(size_t)m * H_ + h] = h_new;
            else if (g == 2) hidB    [(size_t)m * H_ + h] = f2bf(h_new);
        }
      }
    }
}

// ---------------------------------------------------------------------------
// GEMM2: out = hidB @ WhyB^T + b   (128x128 m97-style, N too small for 256^2)
// ---------------------------------------------------------------------------
__global__ __launch_bounds__(256) void out_mm_bf16(
    const ushort* __restrict__ A, const ushort* __restrict__ Bm,
    const float* __restrict__ bw, float* __restrict__ out)
{
    __shared__ ushort As[128 * 32];
    __shared__ ushort Bs[128 * 32];
    const int tid  = threadIdx.x;
    const int lane = tid & 63;
    const int w    = tid >> 6;
    const int wm = w >> 1, wn = w & 1;
    const int blkN = blockIdx.x, blkM = blockIdx.y;
    const int srow = w * 16 + (lane >> 2);
    const int scol = (lane & 3) * 8;

    v4f acc[4][4];
    #pragma unroll
    for (int i = 0; i < 4; ++i)
      #pragma unroll
      for (int j = 0; j < 4; ++j) acc[i][j] = (v4f)0.f;

    for (int k0 = 0; k0 < H_; k0 += 32) {
        #pragma unroll
        for (int it = 0; it < 2; ++it) {
            const int row = it * 64 + srow;
            gload16(A  + (size_t)(blkM * 128 + row) * H_ + k0 + scol,
                    &As[w * 512 + it * 2048]);
            gload16(Bm + (size_t)(blkN * 128 + row) * H_ + k0 + scol,
                    &Bs[w * 512 + it * 2048]);
        }
        __syncthreads();
        v8s afr[4], bfr[4];
        #pragma unroll
        for (int i = 0; i < 4; ++i)
            afr[i] = *(const v8s*)&As[(wm * 64 + i * 16 + (lane & 15)) * 32 + (lane >> 4) * 8];
        #pragma unroll
        for (int j = 0; j < 4; ++j)
            bfr[j] = *(const v8s*)&Bs[(wn * 64 + j * 16 + (lane & 15)) * 32 + (lane >> 4) * 8];
        #pragma unroll
        for (int i = 0; i < 4; ++i)
          #pragma unroll
          for (int j = 0; j < 4; ++j)
            acc[i][j] = __builtin_amdgcn_mfma_f32_16x16x32_bf16(afr[i], bfr[j], acc[i][j], 0, 0, 0);
        __syncthreads();
    }
    #pragma unroll
    for (int i = 0; i < 4; ++i) {
      #pragma unroll
      for (int r = 0; r < 4; ++r) {
        const int m = blkM * 128 + wm * 64 + i * 16 + (lane >> 4) * 4 + r;
        #pragma unroll
        for (int j = 0; j < 4; ++j) {
            const int n = blkN * 128 + wn * 64 + j * 16 + (lane & 15);
            out[(size_t)m * O_ + n] = acc[i][j][r] + bw[n];
        }
      }
    }
}

extern "C" void kernel_launch(void* const* d_in, const int* in_sizes, int n_in,
                              void* d_out, int out_size, void* d_ws, size_t ws_size,
                              hipStream_t stream) {
    const float* x   = (const float*)d_in[0];
    const float* hs  = (const float*)d_in[1];
    const float* cs  = (const float*)d_in[2];
    const float* Wxi = (const float*)d_in[3];
    const float* bxi = (const float*)d_in[4];
    const float* Whi = (const float*)d_in[5];
    const float* Wxf = (const float*)d_in[6];
    const float* bxf = (const float*)d_in[7];
    const float* Whf = (const float*)d_in[8];
    const float* Wxc = (const float*)d_in[9];
    const float* bxc = (const float*)d_in[10];
    const float* Whc = (const float*)d_in[11];
    const float* Wxo = (const float*)d_in[12];
    const float* bxo = (const float*)d_in[13];
    const float* Who = (const float*)d_in[14];
    const float* Why = (const float*)d_in[15];
    const float* bwy = (const float*)d_in[16];

    float* out      = (float*)d_out;
    float* hid_out  = out + (size_t)B_ * O_;
    float* cell_out = hid_out + (size_t)B_ * H_;

    const size_t szW = (size_t)N1 * K1;
    const size_t szX = (size_t)B_ * K1;
    const size_t szY = (size_t)O_ * H_;

    ushort* Wcat = (ushort*)d_ws;
    ushort* Xcat = Wcat + szW;
    ushort* WhyB = Xcat + szX;
    ushort* HidB = WhyB + szY;

    convert_w<<<dim3(N1), 384, 0, stream>>>(Wxi, Whi, Wxf, Whf, Wxc, Whc, Wxo, Who, Wcat);
    convert_x<<<dim3(B_), 384, 0, stream>>>(x, hs, Xcat);
    convert_y<<<dim3(O_), 256, 0, stream>>>(Why, WhyB);

    gates_mm_256<<<dim3((N1 / 256) * (B_ / 256)), 512, 0, stream>>>(
        Xcat, Wcat, cs, bxi, bxf, bxc, bxo, hid_out, cell_out, HidB);
    out_mm_bf16<<<dim3(O_ / 128, B_ / 128), 256, 0, stream>>>(
        HidB, WhyB, bwy, out);
}

// Round 5
// 498.180 us; speedup vs baseline: 1.0024x; 1.0024x over previous
//
#include <hip/hip_runtime.h>
#include <hip/hip_bf16.h>

#define B_ 4096
#define I_ 1024
#define H_ 2048
#define O_ 1024
#define K1 (I_ + H_)   // 3072
#define N1 (4 * H_)    // 8192
#define NKT (K1 / 64)  // 48 K-tiles of 64

typedef short v8s __attribute__((ext_vector_type(8)));
typedef float v4f __attribute__((ext_vector_type(4)));

__device__ __forceinline__ ushort f2bf(float f) {
    unsigned u = __float_as_uint(f);
    u += 0x7fffu + ((u >> 16) & 1u);   // RNE
    return (ushort)(u >> 16);
}
__device__ __forceinline__ float sigm(float x) { return 1.f / (1.f + __expf(-x)); }
__device__ __forceinline__ float tanh_f(float x) {
    x = fminf(15.f, fmaxf(-15.f, x));
    float e = __expf(2.f * x);
    return (e - 1.f) / (e + 1.f);
}
__device__ __forceinline__ void gload16(const void* g, void* l) {
    __builtin_amdgcn_global_load_lds(
        (const __attribute__((address_space(1))) void*)g,
        (__attribute__((address_space(3))) void*)l, 16, 0, 0);
}

// ---------------------------------------------------------------- conversion
__global__ __launch_bounds__(384) void convert_w(
    const float* __restrict__ Wxi, const float* __restrict__ Whi,
    const float* __restrict__ Wxf, const float* __restrict__ Whf,
    const float* __restrict__ Wxc, const float* __restrict__ Whc,
    const float* __restrict__ Wxo, const float* __restrict__ Who,
    ushort* __restrict__ Wcat)
{
    const int n = blockIdx.x;          // 0..8191
    const int k = threadIdx.x * 8;     // 0..3064
    const int h = n >> 2, g = n & 3;
    const float* src;
    if (k < I_) {
        const float* W = (g == 0) ? Wxi : (g == 1) ? Wxf : (g == 2) ? Wxc : Wxo;
        src = W + (size_t)h * I_ + k;
    } else {
        const float* W = (g == 0) ? Whi : (g == 1) ? Whf : (g == 2) ? Whc : Who;
        src = W + (size_t)h * H_ + (k - I_);
    }
    float4 a = *(const float4*)src;
    float4 b = *(const float4*)(src + 4);
    *(ushort4*)&Wcat[(size_t)n * K1 + k] =
        make_ushort4(f2bf(a.x), f2bf(a.y), f2bf(a.z), f2bf(a.w));
    *(ushort4*)&Wcat[(size_t)n * K1 + k + 4] =
        make_ushort4(f2bf(b.x), f2bf(b.y), f2bf(b.z), f2bf(b.w));
}

__global__ __launch_bounds__(384) void convert_x(
    const float* __restrict__ x, const float* __restrict__ hs, ushort* __restrict__ Xcat)
{
    const int m = blockIdx.x;
    const int k = threadIdx.x * 8;
    const float* src = (k < I_) ? (x + (size_t)m * I_ + k)
                                : (hs + (size_t)m * H_ + (k - I_));
    float4 a = *(const float4*)src;
    float4 b = *(const float4*)(src + 4);
    *(ushort4*)&Xcat[(size_t)m * K1 + k] =
        make_ushort4(f2bf(a.x), f2bf(a.y), f2bf(a.z), f2bf(a.w));
    *(ushort4*)&Xcat[(size_t)m * K1 + k + 4] =
        make_ushort4(f2bf(b.x), f2bf(b.y), f2bf(b.z), f2bf(b.w));
}

__global__ __launch_bounds__(256) void convert_y(
    const float* __restrict__ Why, ushort* __restrict__ WhyB)
{
    const int n = blockIdx.x;
    const int k = threadIdx.x * 8;
    const float* src = Why + (size_t)n * H_ + k;
    float4 a = *(const float4*)src;
    float4 b = *(const float4*)(src + 4);
    *(ushort4*)&WhyB[(size_t)n * H_ + k] =
        make_ushort4(f2bf(a.x), f2bf(a.y), f2bf(a.z), f2bf(a.w));
    *(ushort4*)&WhyB[(size_t)n * H_ + k + 4] =
        make_ushort4(f2bf(b.x), f2bf(b.y), f2bf(b.z), f2bf(b.w));
}

// ---------------------------------------------------------------------------
// GEMM1: 256x256 tile, BK=64, 8 waves (2M x 4N), 2 LDS buffers, 4 phases per
// K-tile. Half-tile = [128 rows][64 cols] bf16, row stride 128B, XOR-swizzle
// byte ^= ((row&7)<<4) applied to SOURCE address (dest linear, m104 contract)
// and to the ds_read address (same involution both sides).
// Stages for tile t+1 issue at t's phases 0-1 (3-4 phase slack); single
// vmcnt(0)+barrier at each K-tile boundary. Epilogue: LDS-staged coalesced
// writes (fixes 6x write amplification).
// ---------------------------------------------------------------------------

// ldsoff in ushorts, half-tile region = 8192 ushorts (16KB)
#define STAGE_H(SRC, ROWBASE, TCOL, LDSOFF) {                                 \
    gload16(SRC + (size_t)((ROWBASE) + srow0) * K1 + (TCOL) + scolU,          \
            (ushort*)lds + (LDSOFF) + tid * 8);                               \
    gload16(SRC + (size_t)((ROWBASE) + srow1) * K1 + (TCOL) + scolU,          \
            (ushort*)lds + (LDSOFF) + 4096 + tid * 8);                        \
}

__global__ __launch_bounds__(512, 2) void gates_mm_256(
    const ushort* __restrict__ A, const ushort* __restrict__ Bm,
    const float* __restrict__ cs,
    const float* __restrict__ bxi, const float* __restrict__ bxf,
    const float* __restrict__ bxc, const float* __restrict__ bxo,
    float* __restrict__ hid_out, float* __restrict__ cell_out,
    ushort* __restrict__ hidB)
{
    __shared__ ushort lds[65536];   // 128 KB: buf0 64KB | buf1 64KB
                                    // buf b: A at b*32768, B at b*32768+16384

    const int tid  = threadIdx.x;
    const int lane = tid & 63;
    const int w    = tid >> 6;          // wave 0..7
    const int wm   = w >> 2;            // 0..1  (M half, 128 rows)
    const int wn   = w & 3;             // 0..3  (N quarter, 64 cols)

    // XCD-aware block swizzle (512 blocks, 512%8==0)
    const int nwg = gridDim.x;
    const int xid = (blockIdx.x & 7) * (nwg >> 3) + (blockIdx.x >> 3);
    const int blkM = xid & 15;          // 16 M-blocks
    const int blkN = xid >> 4;          // 32 N-blocks

    // ---- staging geometry (per half-tile; dest linear, source pre-swizzled)
    const int srow0 = tid >> 3;                                  // 0..63
    const int srow1 = srow0 + 64;
    const int scolU = ((((tid & 7) * 16) ^ ((srow0 & 7) << 4)) >> 1);
    const int aRow0 = blkM * 256;
    const int bRow0 = blkN * 256;

    // ---- fragment read offsets (ushort units), same XOR on read side
    const int l15 = lane & 15, l4 = lane >> 4;
    const int flip = (l15 & 7) << 4;
    const int cbU0 = (((l4 * 16)      ) ^ flip) >> 1;
    const int cbU1 = (((l4 * 16) + 64 ) ^ flip) >> 1;
    const int aBaseU = wm * 8192 + l15 * 64;                       // within buf A region
    const int bBaseU = 16384 + (wn >> 1) * 8192 + (wn & 1) * 4096 + l15 * 64;

    v4f acc[8][4];
    #pragma unroll
    for (int mi = 0; mi < 8; ++mi)
      #pragma unroll
      for (int ni = 0; ni < 4; ++ni) acc[mi][ni] = (v4f)0.f;

    // ---- prologue: stage tile 0 into buf 0 (A0,A1,B0,B1)
    STAGE_H(A,  aRow0,       0, 0)
    STAGE_H(A,  aRow0 + 128, 0, 8192)
    STAGE_H(Bm, bRow0,       0, 16384)
    STAGE_H(Bm, bRow0 + 128, 0, 16384 + 8192)

    #pragma unroll 1
    for (int t = 0; t < NKT; ++t) {
        const ushort* bufc = (const ushort*)lds + (t & 1) * 32768;
        const int bufnOff  = ((t & 1) ^ 1) * 32768;
        const int tcol     = (t + 1) * 64;
        v8s bfr[4][2];

        // ===== phase 0: K-tile boundary sync; stage A(t+1); load B frags + A mi0-1
        asm volatile("s_waitcnt vmcnt(0)" ::: "memory");
        __builtin_amdgcn_s_barrier();
        __builtin_amdgcn_sched_barrier(0);
        if (t < NKT - 1) {
            STAGE_H(A, aRow0,       tcol, bufnOff)
            STAGE_H(A, aRow0 + 128, tcol, bufnOff + 8192)
        }
        #pragma unroll
        for (int ni = 0; ni < 4; ++ni) {
            bfr[ni][0] = *(const v8s*)&bufc[bBaseU + ni * 1024 + cbU0];
            bfr[ni][1] = *(const v8s*)&bufc[bBaseU + ni * 1024 + cbU1];
        }
        {
            v8s af00 = *(const v8s*)&bufc[aBaseU + 0 * 1024 + cbU0];
            v8s af01 = *(const v8s*)&bufc[aBaseU + 0 * 1024 + cbU1];
            v8s af10 = *(const v8s*)&bufc[aBaseU + 1 * 1024 + cbU0];
            v8s af11 = *(const v8s*)&bufc[aBaseU + 1 * 1024 + cbU1];
            __builtin_amdgcn_s_setprio(1);
            #pragma unroll
            for (int ni = 0; ni < 4; ++ni) {
                acc[0][ni] = __builtin_amdgcn_mfma_f32_16x16x32_bf16(af00, bfr[ni][0], acc[0][ni], 0, 0, 0);
                acc[0][ni] = __builtin_amdgcn_mfma_f32_16x16x32_bf16(af01, bfr[ni][1], acc[0][ni], 0, 0, 0);
                acc[1][ni] = __builtin_amdgcn_mfma_f32_16x16x32_bf16(af10, bfr[ni][0], acc[1][ni], 0, 0, 0);
                acc[1][ni] = __builtin_amdgcn_mfma_f32_16x16x32_bf16(af11, bfr[ni][1], acc[1][ni], 0, 0, 0);
            }
            __builtin_amdgcn_s_setprio(0);
        }

        // ===== phase 1: stage B(t+1); A mi2-3
        __builtin_amdgcn_s_barrier();
        __builtin_amdgcn_sched_barrier(0);
        if (t < NKT - 1) {
            STAGE_H(Bm, bRow0,       tcol, bufnOff + 16384)
            STAGE_H(Bm, bRow0 + 128, tcol, bufnOff + 16384 + 8192)
        }
        {
            v8s af00 = *(const v8s*)&bufc[aBaseU + 2 * 1024 + cbU0];
            v8s af01 = *(const v8s*)&bufc[aBaseU + 2 * 1024 + cbU1];
            v8s af10 = *(const v8s*)&bufc[aBaseU + 3 * 1024 + cbU0];
            v8s af11 = *(const v8s*)&bufc[aBaseU + 3 * 1024 + cbU1];
            __builtin_amdgcn_s_setprio(1);
            #pragma unroll
            for (int ni = 0; ni < 4; ++ni) {
                acc[2][ni] = __builtin_amdgcn_mfma_f32_16x16x32_bf16(af00, bfr[ni][0], acc[2][ni], 0, 0, 0);
                acc[2][ni] = __builtin_amdgcn_mfma_f32_16x16x32_bf16(af01, bfr[ni][1], acc[2][ni], 0, 0, 0);
                acc[3][ni] = __builtin_amdgcn_mfma_f32_16x16x32_bf16(af10, bfr[ni][0], acc[3][ni], 0, 0, 0);
                acc[3][ni] = __builtin_amdgcn_mfma_f32_16x16x32_bf16(af11, bfr[ni][1], acc[3][ni], 0, 0, 0);
            }
            __builtin_amdgcn_s_setprio(0);
        }

        // ===== phase 2: A mi4-5
        __builtin_amdgcn_s_barrier();
        __builtin_amdgcn_sched_barrier(0);
        {
            v8s af00 = *(const v8s*)&bufc[aBaseU + 4 * 1024 + cbU0];
            v8s af01 = *(const v8s*)&bufc[aBaseU + 4 * 1024 + cbU1];
            v8s af10 = *(const v8s*)&bufc[aBaseU + 5 * 1024 + cbU0];
            v8s af11 = *(const v8s*)&bufc[aBaseU + 5 * 1024 + cbU1];
            __builtin_amdgcn_s_setprio(1);
            #pragma unroll
            for (int ni = 0; ni < 4; ++ni) {
                acc[4][ni] = __builtin_amdgcn_mfma_f32_16x16x32_bf16(af00, bfr[ni][0], acc[4][ni], 0, 0, 0);
                acc[4][ni] = __builtin_amdgcn_mfma_f32_16x16x32_bf16(af01, bfr[ni][1], acc[4][ni], 0, 0, 0);
                acc[5][ni] = __builtin_amdgcn_mfma_f32_16x16x32_bf16(af10, bfr[ni][0], acc[5][ni], 0, 0, 0);
                acc[5][ni] = __builtin_amdgcn_mfma_f32_16x16x32_bf16(af11, bfr[ni][1], acc[5][ni], 0, 0, 0);
            }
            __builtin_amdgcn_s_setprio(0);
        }

        // ===== phase 3: A mi6-7
        __builtin_amdgcn_s_barrier();
        __builtin_amdgcn_sched_barrier(0);
        {
            v8s af00 = *(const v8s*)&bufc[aBaseU + 6 * 1024 + cbU0];
            v8s af01 = *(const v8s*)&bufc[aBaseU + 6 * 1024 + cbU1];
            v8s af10 = *(const v8s*)&bufc[aBaseU + 7 * 1024 + cbU0];
            v8s af11 = *(const v8s*)&bufc[aBaseU + 7 * 1024 + cbU1];
            __builtin_amdgcn_s_setprio(1);
            #pragma unroll
            for (int ni = 0; ni < 4; ++ni) {
                acc[6][ni] = __builtin_amdgcn_mfma_f32_16x16x32_bf16(af00, bfr[ni][0], acc[6][ni], 0, 0, 0);
                acc[6][ni] = __builtin_amdgcn_mfma_f32_16x16x32_bf16(af01, bfr[ni][1], acc[6][ni], 0, 0, 0);
                acc[7][ni] = __builtin_amdgcn_mfma_f32_16x16x32_bf16(af10, bfr[ni][0], acc[7][ni], 0, 0, 0);
                acc[7][ni] = __builtin_amdgcn_mfma_f32_16x16x32_bf16(af11, bfr[ni][1], acc[7][ni], 0, 0, 0);
            }
            __builtin_amdgcn_s_setprio(0);
        }
    }

    // =========================== fused LSTM epilogue ===========================
    // LDS-staged coalesced writes: per M-half, cs tile in, c/h/hB tiles out.
    float*  csT = (float*)lds;                 // [128][64] f32, 32KB
    float*  cT  = (float*)lds + 8192;          // 32KB
    float*  hT  = (float*)lds + 16384;         // 32KB
    ushort* hbT = (ushort*)((float*)lds + 24576);  // [128][64] bf16, 16KB

    const int g = lane & 3;
    const int q = lane & 60;
    int hj[4], hl[4]; float biasj[4];
    #pragma unroll
    for (int ni = 0; ni < 4; ++ni) {
        const int nn = blkN * 256 + wn * 64 + ni * 16 + l15;
        hj[ni] = nn >> 2;
        hl[ni] = (wn * 64 + ni * 16 + l15) >> 2;   // 0..63
        const float* bp = (g == 0) ? bxi : (g == 1) ? bxf : (g == 2) ? bxc : bxo;
        biasj[ni] = bp[hj[ni]];
    }
    const int Mbase = blkM * 256;
    const int Hg0   = blkN * 64;
    const int erow  = tid >> 2;            // 0..127
    const int ecol  = (tid & 3) * 16;      // 0,16,32,48

    #pragma unroll 1
    for (int mh = 0; mh < 2; ++mh) {
        __syncthreads();
        // coop-load cs tile [128][64] coalesced
        {
            const float* src = cs + (size_t)(Mbase + mh * 128 + erow) * H_ + Hg0 + ecol;
            #pragma unroll
            for (int qq = 0; qq < 4; ++qq)
                *(float4*)&csT[erow * 64 + ecol + qq * 4] = *(const float4*)(src + qq * 4);
        }
        __syncthreads();
        if (wm == mh) {
            #pragma unroll
            for (int mi = 0; mi < 8; ++mi) {
              #pragma unroll
              for (int r = 0; r < 4; ++r) {
                const int ml = mi * 16 + l4 * 4 + r;     // row in half
                #pragma unroll
                for (int ni = 0; ni < 4; ++ni) {
                    const float v = acc[mi][ni][r] + biasj[ni];
                    const float gi = __shfl(v, q + 0, 64);
                    const float gf = __shfl(v, q + 1, 64);
                    const float gc = __shfl(v, q + 2, 64);
                    const float go = __shfl(v, q + 3, 64);
                    const float Ig = sigm(gi), Fg = sigm(gf);
                    const float Cg = tanh_f(gc), Og = sigm(go);
                    const float c_old = csT[ml * 64 + hl[ni]];
                    const float c_new = Fg * c_old + Ig * Cg;
                    const float h_new = Og * tanh_f(c_new);
                    if (g == 0)      cT [ml * 64 + hl[ni]] = c_new;
                    else if (g == 1) hT [ml * 64 + hl[ni]] = h_new;
                    else if (g == 2) hbT[ml * 64 + hl[ni]] = f2bf(h_new);
                }
              }
            }
        }
        __syncthreads();
        // coop-store coalesced
        {
            const size_t gof = (size_t)(Mbase + mh * 128 + erow) * H_ + Hg0 + ecol;
            #pragma unroll
            for (int qq = 0; qq < 4; ++qq) {
                *(float4*)&cell_out[gof + qq * 4] = *(const float4*)&cT[erow * 64 + ecol + qq * 4];
                *(float4*)&hid_out [gof + qq * 4] = *(const float4*)&hT[erow * 64 + ecol + qq * 4];
            }
            *(uint4*)&hidB[gof]     = *(const uint4*)&hbT[erow * 64 + ecol];
            *(uint4*)&hidB[gof + 8] = *(const uint4*)&hbT[erow * 64 + ecol + 8];
        }
    }
}

// ---------------------------------------------------------------------------
// GEMM2: out = hidB @ WhyB^T + b   (128x128 m97-style)
// ---------------------------------------------------------------------------
__global__ __launch_bounds__(256) void out_mm_bf16(
    const ushort* __restrict__ A, const ushort* __restrict__ Bm,
    const float* __restrict__ bw, float* __restrict__ out)
{
    __shared__ ushort As[128 * 32];
    __shared__ ushort Bs[128 * 32];
    const int tid  = threadIdx.x;
    const int lane = tid & 63;
    const int w    = tid >> 6;
    const int wm = w >> 1, wn = w & 1;
    const int blkN = blockIdx.x, blkM = blockIdx.y;
    const int srow = w * 16 + (lane >> 2);
    const int scol = (lane & 3) * 8;

    v4f acc[4][4];
    #pragma unroll
    for (int i = 0; i < 4; ++i)
      #pragma unroll
      for (int j = 0; j < 4; ++j) acc[i][j] = (v4f)0.f;

    for (int k0 = 0; k0 < H_; k0 += 32) {
        #pragma unroll
        for (int it = 0; it < 2; ++it) {
            const int row = it * 64 + srow;
            gload16(A  + (size_t)(blkM * 128 + row) * H_ + k0 + scol,
                    &As[w * 512 + it * 2048]);
            gload16(Bm + (size_t)(blkN * 128 + row) * H_ + k0 + scol,
                    &Bs[w * 512 + it * 2048]);
        }
        __syncthreads();
        v8s afr[4], bfr[4];
        #pragma unroll
        for (int i = 0; i < 4; ++i)
            afr[i] = *(const v8s*)&As[(wm * 64 + i * 16 + (lane & 15)) * 32 + (lane >> 4) * 8];
        #pragma unroll
        for (int j = 0; j < 4; ++j)
            bfr[j] = *(const v8s*)&Bs[(wn * 64 + j * 16 + (lane & 15)) * 32 + (lane >> 4) * 8];
        #pragma unroll
        for (int i = 0; i < 4; ++i)
          #pragma unroll
          for (int j = 0; j < 4; ++j)
            acc[i][j] = __builtin_amdgcn_mfma_f32_16x16x32_bf16(afr[i], bfr[j], acc[i][j], 0, 0, 0);
        __syncthreads();
    }
    #pragma unroll
    for (int i = 0; i < 4; ++i) {
      #pragma unroll
      for (int r = 0; r < 4; ++r) {
        const int m = blkM * 128 + wm * 64 + i * 16 + (lane >> 4) * 4 + r;
        #pragma unroll
        for (int j = 0; j < 4; ++j) {
            const int n = blkN * 128 + wn * 64 + j * 16 + (lane & 15);
            out[(size_t)m * O_ + n] = acc[i][j][r] + bw[n];
        }
      }
    }
}

extern "C" void kernel_launch(void* const* d_in, const int* in_sizes, int n_in,
                              void* d_out, int out_size, void* d_ws, size_t ws_size,
                              hipStream_t stream) {
    const float* x   = (const float*)d_in[0];
    const float* hs  = (const float*)d_in[1];
    const float* cs  = (const float*)d_in[2];
    const float* Wxi = (const float*)d_in[3];
    const float* bxi = (const float*)d_in[4];
    const float* Whi = (const float*)d_in[5];
    const float* Wxf = (const float*)d_in[6];
    const float* bxf = (const float*)d_in[7];
    const float* Whf = (const float*)d_in[8];
    const float* Wxc = (const float*)d_in[9];
    const float* bxc = (const float*)d_in[10];
    const float* Whc = (const float*)d_in[11];
    const float* Wxo = (const float*)d_in[12];
    const float* bxo = (const float*)d_in[13];
    const float* Who = (const float*)d_in[14];
    const float* Why = (const float*)d_in[15];
    const float* bwy = (const float*)d_in[16];

    float* out      = (float*)d_out;
    float* hid_out  = out + (size_t)B_ * O_;
    float* cell_out = hid_out + (size_t)B_ * H_;

    const size_t szW = (size_t)N1 * K1;
    const size_t szX = (size_t)B_ * K1;
    const size_t szY = (size_t)O_ * H_;

    ushort* Wcat = (ushort*)d_ws;
    ushort* Xcat = Wcat + szW;
    ushort* WhyB = Xcat + szX;
    ushort* HidB = WhyB + szY;

    convert_w<<<dim3(N1), 384, 0, stream>>>(Wxi, Whi, Wxf, Whf, Wxc, Whc, Wxo, Who, Wcat);
    convert_x<<<dim3(B_), 384, 0, stream>>>(x, hs, Xcat);
    convert_y<<<dim3(O_), 256, 0, stream>>>(Why, WhyB);

    gates_mm_256<<<dim3((N1 / 256) * (B_ / 256)), 512, 0, stream>>>(
        Xcat, Wcat, cs, bxi, bxf, bxc, bxo, hid_out, cell_out, HidB);
    out_mm_bf16<<<dim3(O_ / 128, B_ / 128), 256, 0, stream>>>(
        HidB, WhyB, bwy, out);
}